// Round 11
// baseline (237.681 us; speedup 1.0000x reference)
//
#include <hip/hip_runtime.h>
#include <hip/hip_fp16.h>

#define N_NODES 100000
#define N_EDGES 1600000
#define NPB 128                                   // nodes per dst-bucket
#define NBK ((N_NODES + NPB - 1) / NPB)           // 782 buckets
#define FBLK 256                                  // fill blocks; FBLK*EPB == N_EDGES exactly
#define EPB (N_EDGES / FBLK)                      // 6250 edges per fill block
#define CAP 4096                                  // LDS capacity per bucket (padded fill ~2500, 4096 is 30+ sigma)
#define ESTR 3072                                 // esrc stride per bucket (padded fill mean ~2494, sigma ~52 -> 11 sigma)
#define SENT 100000                               // sentinel row (zeroed in each ys buffer by its producer)
#define LSTR (NBK + 1)                            // stride of per-block local-offset table L

typedef _Float16 h8 __attribute__((ext_vector_type(8)));
typedef float f4v __attribute__((ext_vector_type(4)));
typedef float f4n __attribute__((ext_vector_type(4)));   // native vec4 for nontemporal builtins

// ---------------- pass 1: fused histogram + local scan + LDS counting sort -> block-major tmp ----------------
// 512 threads/block: build runs at 1 block/CU (257 blocks), so per-block critical path is the kernel
// duration; doubling threads halves the edge-loop rounds and scan chunks. Extra block: transposes.

__global__ void __launch_bounds__(512) build_kernel(const int* __restrict__ src, const int* __restrict__ dst,
                                                    int* __restrict__ L, int* __restrict__ tmp,
                                                    const float* __restrict__ W0, const float* __restrict__ W1,
                                                    const float* __restrict__ W2, __half* __restrict__ wt0,
                                                    __half* __restrict__ wt1, __half* __restrict__ wt2) {
    if (blockIdx.x == FBLK) {
        const int t = threadIdx.x;
        for (int i = t; i < 14336; i += 512) {
            if (i < 8192)       { int k = i / 64, c = i % 64;                 wt0[c * 128 + k] = __float2half(W0[i]); }
            else if (i < 12288) { int j = i - 8192;  int k = j / 64, c = j % 64; wt1[c * 64 + k] = __float2half(W1[j]); }
            else                { int j = i - 12288; int k = j / 32, c = j % 32; wt2[c * 64 + k] = __float2half(W2[j]); }
        }
        return;
    }
    __shared__ int h[NBK];
    __shared__ int sc[512];
    __shared__ int sbuf[EPB];
    const int k = blockIdx.x;
    const int tid = threadIdx.x;
    for (int i = tid; i < NBK; i += 512) h[i] = 0;
    __syncthreads();
    const int e0 = k * EPB;
    for (int e = e0 + tid; e < e0 + EPB; e += 512) atomicAdd(&h[dst[e] >> 7], 1);
    __syncthreads();

    // exclusive scan of h over NBK buckets: write L[k][*], convert h in place to cursors
    int run = 0;
    for (int c0 = 0; c0 < NBK; c0 += 512) {
        int idx = c0 + tid;
        int v = (idx < NBK) ? h[idx] : 0;
        sc[tid] = v;
        __syncthreads();
        for (int off = 1; off < 512; off <<= 1) {
            int u = (tid >= off) ? sc[tid - off] : 0;
            __syncthreads();
            sc[tid] += u;
            __syncthreads();
        }
        if (idx < NBK) {
            int excl = run + sc[tid] - v;
            L[k * LSTR + idx] = excl;
            h[idx] = excl;                     // own slot only
        }
        int chunktot = sc[511];
        __syncthreads();
        run += chunktot;
    }
    if (tid == 0) L[k * LSTR + NBK] = run;     // == EPB

    // counting sort into LDS, then coalesced write
    for (int e = e0 + tid; e < e0 + EPB; e += 512) {
        int s = src[e];
        int d = dst[e];
        int pos = atomicAdd(&h[d >> 7], 1);
        sbuf[pos] = s | ((d & (NPB - 1)) << 20);
    }
    __syncthreads();
    for (int i = tid; i < EPB; i += 512) tmp[e0 + i] = sbuf[i];
}

// ---------------- pass 2: segment-gather + 8-padded per-node layout -> esrc (stride ESTR), rse, dis ----------------

__global__ void __launch_bounds__(256) bucketfin_kernel(const int* __restrict__ tmp, const int* __restrict__ L,
                                                        int* __restrict__ esrc, int2* __restrict__ rse,
                                                        float* __restrict__ dis, int n) {
    __shared__ int buf[CAP];
    __shared__ int buf2[CAP];
    __shared__ int cnt[NPB];
    __shared__ int sc[NPB];
    __shared__ int rp8[NPB];
    __shared__ int fillc[NPB];
    __shared__ int segb[256];
    const int b = blockIdx.x;
    const int tid = threadIdx.x;
    const int d0 = b * NPB;
    const int nd = min(NPB, n - d0);
    const int base = b * ESTR;

    const int lb = L[tid * LSTR + b];
    const int le = L[tid * LSTR + b + 1];
    const int c  = le - lb;

    segb[tid] = c;
    __syncthreads();
    for (int off = 1; off < 256; off <<= 1) {
        int u = (tid >= off) ? segb[tid - off] : 0;
        __syncthreads();
        segb[tid] += u;
        __syncthreads();
    }
    const int my0   = segb[tid] - c;
    const int count = segb[255];               // ~2046 << CAP

    for (int i = tid; i < NPB; i += 256) { cnt[i] = 0; fillc[i] = 0; }
    __syncthreads();

    const int* seg = tmp + tid * EPB + lb;
    for (int j = 0; j < c; ++j) buf[my0 + j] = seg[j];
    __syncthreads();
    for (int e = tid; e < count; e += 256) atomicAdd(&cnt[buf[e] >> 20], 1);
    __syncthreads();

    // scan of 8-rounded counts
    int c8 = 0;
    if (tid < NPB) { c8 = (cnt[tid] + 7) & ~7; sc[tid] = c8; }
    __syncthreads();
    for (int off = 1; off < NPB; off <<= 1) {
        int v = (tid < NPB && tid >= off) ? sc[tid - off] : 0;
        __syncthreads();
        if (tid < NPB) sc[tid] += v;
        __syncthreads();
    }
    if (tid < NPB) {
        int excl = sc[tid] - c8;
        rp8[tid] = excl;
        if (tid < nd) {
            rse[d0 + tid] = make_int2(base + excl, base + excl + c8);
            dis[d0 + tid] = rsqrtf((float)cnt[tid] + 1.0f);
        }
    }
    __syncthreads();
    const int tot8 = sc[NPB - 1];              // <= ~2700 << ESTR

    for (int i = tid; i < tot8; i += 256) buf2[i] = SENT;
    __syncthreads();
    for (int e = tid; e < count; e += 256) {
        int w = buf[e];
        int ld = w >> 20;
        int pos = rp8[ld] + atomicAdd(&fillc[ld], 1);
        buf2[pos] = w & 0xFFFFF;
    }
    __syncthreads();
    for (int e = tid; e < tot8; e += 256) esrc[base + e] = buf2[e];
}

// ---------------- MFMA GEMM (layer 0): ys[n,64] = fp16(dis[row] * (x[n,128] @ W)); block 0 zeroes sentinel ----------------

template <typename TIN, int DIN, int DOUT>
__global__ void __launch_bounds__(256) gemm_kernel(const TIN* __restrict__ x,
                                                   const __half* __restrict__ wt16,
                                                   const float* __restrict__ dis,
                                                   __half* __restrict__ ys, int n) {
    constexpr int WS = DIN + 8;
    constexpr int NT = DOUT / 16;
    constexpr int KC = DIN / 32;

    __shared__ _Float16 xls[64 * WS];
    __shared__ _Float16 wls[DOUT * WS];

    const int tid  = threadIdx.x;
    const int row0 = blockIdx.x * 64;

    if (blockIdx.x == 0 && tid < DOUT / 2)     // zero sentinel row (DOUT halves = DOUT/2 ints)
        ((int*)ys)[(long)SENT * (DOUT / 2) + tid] = 0;

    for (int i = tid; i < DOUT * DIN / 8; i += 256) {
        int c = (i * 8) / DIN, k = (i * 8) % DIN;
        *(int4*)&wls[c * WS + k] = *(const int4*)&wt16[c * DIN + k];
    }
    if constexpr (sizeof(TIN) == 4) {
        for (int i = tid; i < 64 * DIN / 4; i += 256) {
            int r = (i * 4) / DIN, k = (i * 4) % DIN;
            float4 v = make_float4(0.f, 0.f, 0.f, 0.f);
            if (row0 + r < n) v = *(const float4*)&x[(long)(row0 + r) * DIN + k];
            _Float16 h[4] = {(_Float16)v.x, (_Float16)v.y, (_Float16)v.z, (_Float16)v.w};
            *(int2*)&xls[r * WS + k] = *(int2*)h;
        }
    } else {
        for (int i = tid; i < 64 * DIN / 8; i += 256) {
            int r = (i * 8) / DIN, k = (i * 8) % DIN;
            int4 v = make_int4(0, 0, 0, 0);
            if (row0 + r < n) v = *(const int4*)&x[(long)(row0 + r) * DIN + k];
            *(int4*)&xls[r * WS + k] = v;
        }
    }
    __syncthreads();

    const int wave = tid >> 6;
    const int lane = tid & 63;
    const int m16  = lane & 15;
    const int quad = lane >> 4;

    f4v acc[NT];
#pragma unroll
    for (int t = 0; t < NT; ++t) acc[t] = (f4v){0.f, 0.f, 0.f, 0.f};

    const int arow = wave * 16 + m16;
#pragma unroll
    for (int kc = 0; kc < KC; ++kc) {
        h8 a = *(const h8*)&xls[arow * WS + kc * 32 + quad * 8];
#pragma unroll
        for (int t = 0; t < NT; ++t) {
            h8 b = *(const h8*)&wls[(t * 16 + m16) * WS + kc * 32 + quad * 8];
            acc[t] = __builtin_amdgcn_mfma_f32_16x16x32_f16(a, b, acc[t], 0, 0, 0);
        }
    }

    float dsv[4];
    int   lrow[4];
#pragma unroll
    for (int reg = 0; reg < 4; ++reg) {
        lrow[reg] = wave * 16 + quad * 4 + reg;
        int grow  = row0 + lrow[reg];
        dsv[reg]  = (grow < n) ? dis[grow] : 0.f;
    }
    __syncthreads();
    _Float16* stage = xls;
#pragma unroll
    for (int t = 0; t < NT; ++t) {
#pragma unroll
        for (int reg = 0; reg < 4; ++reg)
            stage[lrow[reg] * DOUT + t * 16 + m16] = (_Float16)(acc[t][reg] * dsv[reg]);
    }
    __syncthreads();
    for (int i = tid; i < 64 * DOUT / 8; i += 256) {
        int off = i * 8;
        int r = off / DOUT;
        if (row0 + r < n)
            *(int4*)&ys[(long)row0 * DOUT + off] = *(int4*)&stage[off];
    }
}

// ---------------- gather helper ----------------

__device__ __forceinline__ void acc8(int4 w, float* a) {
    __half2* h = (__half2*)&w;
    float2 f0 = __half22float2(h[0]);
    float2 f1 = __half22float2(h[1]);
    float2 f2 = __half22float2(h[2]);
    float2 f3 = __half22float2(h[3]);
    a[0] += f0.x; a[1] += f0.y; a[2] += f1.x; a[3] += f1.y;
    a[4] += f2.x; a[5] += f2.y; a[6] += f3.x; a[7] += f3.y;
}

// ---------------- FUSED gather(64) + GEMM(64->DOUT); index-prefetch pipeline, NT esrc stream ----------------

template <int DOUT>
__global__ void __launch_bounds__(256) fused_gg_kernel(const int2* __restrict__ rse, const int* __restrict__ esrc,
                                                       const __half* __restrict__ ysin, const float* __restrict__ dis,
                                                       const float* __restrict__ bvec, const __half* __restrict__ wt16,
                                                       __half* __restrict__ ysout, int n) {
    constexpr int WS = 72;
    constexpr int NT = DOUT / 16;

    __shared__ _Float16 xls[64 * WS];
    __shared__ _Float16 wls[DOUT * WS];

    const int tid  = threadIdx.x;
    const int row0 = blockIdx.x * 64;

    if (blockIdx.x == 0 && tid < DOUT / 2)
        ((int*)ysout)[(long)SENT * (DOUT / 2) + tid] = 0;

    for (int i = tid; i < DOUT * 64 / 8; i += 256) {
        int c = (i * 8) / 64, k = (i * 8) % 64;
        *(int4*)&wls[c * WS + k] = *(const int4*)&wt16[c * 64 + k];
    }

    // ---- phase A: gather (pipelined, branch-free 8-wide over padded segments) ----
#pragma unroll
    for (int pass = 0; pass < 2; ++pass) {
        const int lrow = pass * 32 + (tid >> 3);
        const int node = row0 + lrow;
        const int sel  = (tid & 7) * 8;
        float a[8] = {0.f, 0.f, 0.f, 0.f, 0.f, 0.f, 0.f, 0.f};
        if (node < n) {
            {
                int4 sw = *(const int4*)&ysin[(long)node * 64 + sel];
                acc8(sw, a);
            }
            const int2 se = rse[node];
            int k = se.x;
            const int kend = se.y;
            if (k < kend) {
                int u0 = __builtin_nontemporal_load(&esrc[k + 0]);
                int u1 = __builtin_nontemporal_load(&esrc[k + 1]);
                int u2 = __builtin_nontemporal_load(&esrc[k + 2]);
                int u3 = __builtin_nontemporal_load(&esrc[k + 3]);
                int u4 = __builtin_nontemporal_load(&esrc[k + 4]);
                int u5 = __builtin_nontemporal_load(&esrc[k + 5]);
                int u6 = __builtin_nontemporal_load(&esrc[k + 6]);
                int u7 = __builtin_nontemporal_load(&esrc[k + 7]);
                for (k += 8; k < kend; k += 8) {
                    int v0 = __builtin_nontemporal_load(&esrc[k + 0]);
                    int v1 = __builtin_nontemporal_load(&esrc[k + 1]);
                    int v2 = __builtin_nontemporal_load(&esrc[k + 2]);
                    int v3 = __builtin_nontemporal_load(&esrc[k + 3]);
                    int v4 = __builtin_nontemporal_load(&esrc[k + 4]);
                    int v5 = __builtin_nontemporal_load(&esrc[k + 5]);
                    int v6 = __builtin_nontemporal_load(&esrc[k + 6]);
                    int v7 = __builtin_nontemporal_load(&esrc[k + 7]);
                    int4 w0 = *(const int4*)&ysin[(long)u0 * 64 + sel];
                    int4 w1 = *(const int4*)&ysin[(long)u1 * 64 + sel];
                    int4 w2 = *(const int4*)&ysin[(long)u2 * 64 + sel];
                    int4 w3 = *(const int4*)&ysin[(long)u3 * 64 + sel];
                    int4 w4 = *(const int4*)&ysin[(long)u4 * 64 + sel];
                    int4 w5 = *(const int4*)&ysin[(long)u5 * 64 + sel];
                    int4 w6 = *(const int4*)&ysin[(long)u6 * 64 + sel];
                    int4 w7 = *(const int4*)&ysin[(long)u7 * 64 + sel];
                    acc8(w0, a); acc8(w1, a); acc8(w2, a); acc8(w3, a);
                    acc8(w4, a); acc8(w5, a); acc8(w6, a); acc8(w7, a);
                    u0 = v0; u1 = v1; u2 = v2; u3 = v3;
                    u4 = v4; u5 = v5; u6 = v6; u7 = v7;
                }
                int4 w0 = *(const int4*)&ysin[(long)u0 * 64 + sel];
                int4 w1 = *(const int4*)&ysin[(long)u1 * 64 + sel];
                int4 w2 = *(const int4*)&ysin[(long)u2 * 64 + sel];
                int4 w3 = *(const int4*)&ysin[(long)u3 * 64 + sel];
                int4 w4 = *(const int4*)&ysin[(long)u4 * 64 + sel];
                int4 w5 = *(const int4*)&ysin[(long)u5 * 64 + sel];
                int4 w6 = *(const int4*)&ysin[(long)u6 * 64 + sel];
                int4 w7 = *(const int4*)&ysin[(long)u7 * 64 + sel];
                acc8(w0, a); acc8(w1, a); acc8(w2, a); acc8(w3, a);
                acc8(w4, a); acc8(w5, a); acc8(w6, a); acc8(w7, a);
            }
            const float di = dis[node];
#pragma unroll
            for (int j = 0; j < 8; ++j)
                a[j] = fmaxf(a[j] * di + bvec[sel + j], 0.0f);
        }
        _Float16 hv[8];
#pragma unroll
        for (int j = 0; j < 8; ++j) hv[j] = (_Float16)a[j];
        *(int4*)&xls[lrow * WS + sel] = *(int4*)hv;
    }
    __syncthreads();

    // ---- phase B: GEMM ----
    const int wave = tid >> 6;
    const int lane = tid & 63;
    const int m16  = lane & 15;
    const int quad = lane >> 4;

    f4v acc[NT];
#pragma unroll
    for (int t = 0; t < NT; ++t) acc[t] = (f4v){0.f, 0.f, 0.f, 0.f};

    const int arow = wave * 16 + m16;
#pragma unroll
    for (int kc = 0; kc < 2; ++kc) {
        h8 av = *(const h8*)&xls[arow * WS + kc * 32 + quad * 8];
#pragma unroll
        for (int t = 0; t < NT; ++t) {
            h8 bv = *(const h8*)&wls[(t * 16 + m16) * WS + kc * 32 + quad * 8];
            acc[t] = __builtin_amdgcn_mfma_f32_16x16x32_f16(av, bv, acc[t], 0, 0, 0);
        }
    }

    float dsv[4];
    int   lr[4];
#pragma unroll
    for (int reg = 0; reg < 4; ++reg) {
        lr[reg]  = wave * 16 + quad * 4 + reg;
        int grow = row0 + lr[reg];
        dsv[reg] = (grow < n) ? dis[grow] : 0.f;
    }
    __syncthreads();
    _Float16* stage = wls;
#pragma unroll
    for (int t = 0; t < NT; ++t) {
#pragma unroll
        for (int reg = 0; reg < 4; ++reg)
            stage[lr[reg] * DOUT + t * 16 + m16] = (_Float16)(acc[t][reg] * dsv[reg]);
    }
    __syncthreads();
    for (int i = tid; i < 64 * DOUT / 8; i += 256) {
        int off = i * 8;
        int r = off / DOUT;
        if (row0 + r < n)
            *(int4*)&ysout[(long)row0 * DOUT + off] = *(int4*)&stage[off];
    }
}

// ---------------- final gather (32-wide), pipelined, NT esrc stream + NT output stores ----------------

__global__ void __launch_bounds__(256) gather4h_kernel(const int2* __restrict__ rse, const int* __restrict__ esrc,
                                                       const __half* __restrict__ ys, const float* __restrict__ dis,
                                                       const float* __restrict__ b, float* __restrict__ out, int n) {
    const int node = blockIdx.x * 64 + (threadIdx.x >> 2);
    const int c = (threadIdx.x & 3) * 8;
    if (node >= n) return;

    float a[8];
    {
        int4 sw = *(const int4*)&ys[(long)node * 32 + c];
        __half2* h = (__half2*)&sw;
        float2 f0 = __half22float2(h[0]);
        float2 f1 = __half22float2(h[1]);
        float2 f2 = __half22float2(h[2]);
        float2 f3 = __half22float2(h[3]);
        a[0] = f0.x; a[1] = f0.y; a[2] = f1.x; a[3] = f1.y;
        a[4] = f2.x; a[5] = f2.y; a[6] = f3.x; a[7] = f3.y;
    }

    const int2 se = rse[node];
    int k = se.x;
    const int kend = se.y;
    if (k < kend) {
        int u0 = __builtin_nontemporal_load(&esrc[k + 0]);
        int u1 = __builtin_nontemporal_load(&esrc[k + 1]);
        int u2 = __builtin_nontemporal_load(&esrc[k + 2]);
        int u3 = __builtin_nontemporal_load(&esrc[k + 3]);
        int u4 = __builtin_nontemporal_load(&esrc[k + 4]);
        int u5 = __builtin_nontemporal_load(&esrc[k + 5]);
        int u6 = __builtin_nontemporal_load(&esrc[k + 6]);
        int u7 = __builtin_nontemporal_load(&esrc[k + 7]);
        for (k += 8; k < kend; k += 8) {
            int v0 = __builtin_nontemporal_load(&esrc[k + 0]);
            int v1 = __builtin_nontemporal_load(&esrc[k + 1]);
            int v2 = __builtin_nontemporal_load(&esrc[k + 2]);
            int v3 = __builtin_nontemporal_load(&esrc[k + 3]);
            int v4 = __builtin_nontemporal_load(&esrc[k + 4]);
            int v5 = __builtin_nontemporal_load(&esrc[k + 5]);
            int v6 = __builtin_nontemporal_load(&esrc[k + 6]);
            int v7 = __builtin_nontemporal_load(&esrc[k + 7]);
            int4 w0 = *(const int4*)&ys[(long)u0 * 32 + c];
            int4 w1 = *(const int4*)&ys[(long)u1 * 32 + c];
            int4 w2 = *(const int4*)&ys[(long)u2 * 32 + c];
            int4 w3 = *(const int4*)&ys[(long)u3 * 32 + c];
            int4 w4 = *(const int4*)&ys[(long)u4 * 32 + c];
            int4 w5 = *(const int4*)&ys[(long)u5 * 32 + c];
            int4 w6 = *(const int4*)&ys[(long)u6 * 32 + c];
            int4 w7 = *(const int4*)&ys[(long)u7 * 32 + c];
            acc8(w0, a); acc8(w1, a); acc8(w2, a); acc8(w3, a);
            acc8(w4, a); acc8(w5, a); acc8(w6, a); acc8(w7, a);
            u0 = v0; u1 = v1; u2 = v2; u3 = v3;
            u4 = v4; u5 = v5; u6 = v6; u7 = v7;
        }
        int4 w0 = *(const int4*)&ys[(long)u0 * 32 + c];
        int4 w1 = *(const int4*)&ys[(long)u1 * 32 + c];
        int4 w2 = *(const int4*)&ys[(long)u2 * 32 + c];
        int4 w3 = *(const int4*)&ys[(long)u3 * 32 + c];
        int4 w4 = *(const int4*)&ys[(long)u4 * 32 + c];
        int4 w5 = *(const int4*)&ys[(long)u5 * 32 + c];
        int4 w6 = *(const int4*)&ys[(long)u6 * 32 + c];
        int4 w7 = *(const int4*)&ys[(long)u7 * 32 + c];
        acc8(w0, a); acc8(w1, a); acc8(w2, a); acc8(w3, a);
        acc8(w4, a); acc8(w5, a); acc8(w6, a); acc8(w7, a);
    }

    const float di = dis[node];
    f4n o0, o1;
    o0[0] = a[0] * di + b[c + 0];
    o0[1] = a[1] * di + b[c + 1];
    o0[2] = a[2] * di + b[c + 2];
    o0[3] = a[3] * di + b[c + 3];
    o1[0] = a[4] * di + b[c + 4];
    o1[1] = a[5] * di + b[c + 5];
    o1[2] = a[6] * di + b[c + 6];
    o1[3] = a[7] * di + b[c + 7];
    __builtin_nontemporal_store(o0, (f4n*)&out[(long)node * 32 + c]);
    __builtin_nontemporal_store(o1, (f4n*)&out[(long)node * 32 + c + 4]);
}

// ---------------- launch ----------------

extern "C" void kernel_launch(void* const* d_in, const int* in_sizes, int n_in,
                              void* d_out, int out_size, void* d_ws, size_t ws_size,
                              hipStream_t stream) {
    const float* features = (const float*)d_in[0];
    const int*   ei       = (const int*)d_in[1];
    const float* W0 = (const float*)d_in[2];
    const float* b0 = (const float*)d_in[3];
    const float* W1 = (const float*)d_in[4];
    const float* b1 = (const float*)d_in[5];
    const float* W2 = (const float*)d_in[6];
    const float* b2 = (const float*)d_in[7];

    const int* src = ei;             // edge_index[0]
    const int* dst = ei + N_EDGES;   // edge_index[1]

    const int n = N_NODES;

    // workspace (int slots). Aliases (stream-ordered, verified):
    //   tmp aliases ysB (tmp dead after bucketfin; ysB first written by fused#1)
    //   ysC aliases ysA (ysA dead after fused#1; ysC first written by fused#2)
    int*    L    = (int*)d_ws;                        // 256*783 = 200448 -> [0, 200448)
    float*  dis  = (float*)d_ws + 200448;             // [200448, 300800)
    int2*   rse  = (int2*)((int*)d_ws + 300800);      // n int2 = 200704 ints -> [300800, 501504)
    int*    esrc = (int*)d_ws + 501504;               // 782*3072 = 2402304 -> [501504, 2903808)
    __half* ysA  = (__half*)((int*)d_ws + 2903808);   // 100001*64 halves = 3200032 ints
    __half* ysC  = (__half*)((int*)d_ws + 2903808);   // alias
    __half* ysB  = (__half*)((int*)d_ws + 6103840);   // 3200032 ints
    int*    tmp  = (int*)d_ws + 6103840;              // alias (1600000 ints)
    __half* wt0  = (__half*)((int*)d_ws + 9303872);   // 8192 halves
    __half* wt1  = (__half*)((int*)d_ws + 9307968);   // 4096 halves
    __half* wt2  = (__half*)((int*)d_ws + 9310016);   // 2048 halves
    float*  outf = (float*)d_out;                     // N*32 fp32

    // ---- CSR build (2 kernels) ----
    build_kernel<<<FBLK + 1, 512, 0, stream>>>(src, dst, L, tmp, W0, W1, W2, wt0, wt1, wt2);
    bucketfin_kernel<<<NBK, 256, 0, stream>>>(tmp, L, esrc, rse, dis, n);

    // ---- layer 0 GEMM: features(fp32,128) -> ysA ----
    gemm_kernel<float, 128, 64><<<(n + 63) / 64, 256, 0, stream>>>(features, wt0, dis, ysA, n);

    // ---- fused gather(L0)+ReLU+GEMM(L1): ysA -> ysB ----
    fused_gg_kernel<64><<<(n + 63) / 64, 256, 0, stream>>>(rse, esrc, ysA, dis, b0, wt1, ysB, n);

    // ---- fused gather(L1)+ReLU+GEMM(L2): ysB -> ysC ----
    fused_gg_kernel<32><<<(n + 63) / 64, 256, 0, stream>>>(rse, esrc, ysB, dis, b1, wt2, ysC, n);

    // ---- final gather(L2), no ReLU, fp32 out ----
    gather4h_kernel<<<(n + 63) / 64, 256, 0, stream>>>(rse, esrc, ysC, dis, b2, outf, n);
}

// Round 12
// 225.454 us; speedup vs baseline: 1.0542x; 1.0542x over previous
//
#include <hip/hip_runtime.h>
#include <hip/hip_fp16.h>

#define N_NODES 100000
#define N_EDGES 1600000
#define NPB 128                                   // nodes per dst-bucket
#define NBK ((N_NODES + NPB - 1) / NPB)           // 782 buckets
#define FBLK 256                                  // fill blocks; FBLK*EPB == N_EDGES exactly
#define EPB (N_EDGES / FBLK)                      // 6250 edges per fill block
#define CAP 4096                                  // LDS capacity per bucket (padded fill ~2500, 4096 is 30+ sigma)
#define ESTR 3072                                 // esrc stride per bucket (padded fill mean ~2494, sigma ~52 -> 11 sigma)
#define SENT 100000                               // sentinel row (zeroed in each ys buffer by its producer)
#define LSTR (NBK + 1)                            // stride of per-block local-offset table L

typedef _Float16 h8 __attribute__((ext_vector_type(8)));
typedef float f4v __attribute__((ext_vector_type(4)));

// ---------------- pass 1: fused histogram + local scan + LDS counting sort -> block-major tmp ----------------
// int2-vectorized edge streams (EPB*4B = 25000B per block -> 8B aligned). Extra block: transposes.

__global__ void __launch_bounds__(256) build_kernel(const int* __restrict__ src, const int* __restrict__ dst,
                                                    int* __restrict__ L, int* __restrict__ tmp,
                                                    const float* __restrict__ W0, const float* __restrict__ W1,
                                                    const float* __restrict__ W2, __half* __restrict__ wt0,
                                                    __half* __restrict__ wt1, __half* __restrict__ wt2) {
    if (blockIdx.x == FBLK) {
        const int t = threadIdx.x;
        for (int i = t; i < 14336; i += 256) {
            if (i < 8192)       { int k = i / 64, c = i % 64;                 wt0[c * 128 + k] = __float2half(W0[i]); }
            else if (i < 12288) { int j = i - 8192;  int k = j / 64, c = j % 64; wt1[c * 64 + k] = __float2half(W1[j]); }
            else                { int j = i - 12288; int k = j / 32, c = j % 32; wt2[c * 64 + k] = __float2half(W2[j]); }
        }
        return;
    }
    __shared__ int h[NBK];
    __shared__ int sc[256];
    __shared__ int sbuf[EPB];
    const int k = blockIdx.x;
    const int tid = threadIdx.x;
    for (int i = tid; i < NBK; i += 256) h[i] = 0;
    __syncthreads();
    const int e0 = k * EPB;
    const int2* d2 = (const int2*)(dst + e0);
    const int2* s2 = (const int2*)(src + e0);
    for (int i = tid; i < EPB / 2; i += 256) {
        int2 d = d2[i];
        atomicAdd(&h[d.x >> 7], 1);
        atomicAdd(&h[d.y >> 7], 1);
    }
    __syncthreads();

    // exclusive scan of h over NBK buckets: write L[k][*], convert h in place to cursors
    int run = 0;
    for (int c0 = 0; c0 < NBK; c0 += 256) {
        int idx = c0 + tid;
        int v = (idx < NBK) ? h[idx] : 0;
        sc[tid] = v;
        __syncthreads();
        for (int off = 1; off < 256; off <<= 1) {
            int u = (tid >= off) ? sc[tid - off] : 0;
            __syncthreads();
            sc[tid] += u;
            __syncthreads();
        }
        if (idx < NBK) {
            int excl = run + sc[tid] - v;
            L[k * LSTR + idx] = excl;
            h[idx] = excl;                     // own slot only
        }
        int chunktot = sc[255];
        __syncthreads();
        run += chunktot;
    }
    if (tid == 0) L[k * LSTR + NBK] = run;     // == EPB

    // counting sort into LDS (int2 edge reads), then int2 coalesced write
    for (int i = tid; i < EPB / 2; i += 256) {
        int2 d = d2[i];
        int2 s = s2[i];
        int pos = atomicAdd(&h[d.x >> 7], 1);
        sbuf[pos] = s.x | ((d.x & (NPB - 1)) << 20);
        pos = atomicAdd(&h[d.y >> 7], 1);
        sbuf[pos] = s.y | ((d.y & (NPB - 1)) << 20);
    }
    __syncthreads();
    for (int i = tid; i < EPB / 2; i += 256)
        *(int2*)&tmp[e0 + 2 * i] = *(int2*)&sbuf[2 * i];
}

// ---------------- pass 2: segment-gather + 8-padded per-node layout -> esrc (stride ESTR), rse, dis ----------------

__global__ void __launch_bounds__(256) bucketfin_kernel(const int* __restrict__ tmp, const int* __restrict__ L,
                                                        int* __restrict__ esrc, int2* __restrict__ rse,
                                                        float* __restrict__ dis, int n) {
    __shared__ int buf[CAP];
    __shared__ int buf2[CAP];
    __shared__ int cnt[NPB];
    __shared__ int sc[NPB];
    __shared__ int rp8[NPB];
    __shared__ int fillc[NPB];
    __shared__ int segb[256];
    const int b = blockIdx.x;
    const int tid = threadIdx.x;
    const int d0 = b * NPB;
    const int nd = min(NPB, n - d0);
    const int base = b * ESTR;

    const int lb = L[tid * LSTR + b];
    const int le = L[tid * LSTR + b + 1];
    const int c  = le - lb;

    segb[tid] = c;
    __syncthreads();
    for (int off = 1; off < 256; off <<= 1) {
        int u = (tid >= off) ? segb[tid - off] : 0;
        __syncthreads();
        segb[tid] += u;
        __syncthreads();
    }
    const int my0   = segb[tid] - c;
    const int count = segb[255];               // ~2046 << CAP

    for (int i = tid; i < NPB; i += 256) { cnt[i] = 0; fillc[i] = 0; }
    __syncthreads();

    const int* seg = tmp + tid * EPB + lb;
    for (int j = 0; j < c; ++j) buf[my0 + j] = seg[j];
    __syncthreads();
    for (int e = tid; e < count; e += 256) atomicAdd(&cnt[buf[e] >> 20], 1);
    __syncthreads();

    // scan of 8-rounded counts
    int c8 = 0;
    if (tid < NPB) { c8 = (cnt[tid] + 7) & ~7; sc[tid] = c8; }
    __syncthreads();
    for (int off = 1; off < NPB; off <<= 1) {
        int v = (tid < NPB && tid >= off) ? sc[tid - off] : 0;
        __syncthreads();
        if (tid < NPB) sc[tid] += v;
        __syncthreads();
    }
    if (tid < NPB) {
        int excl = sc[tid] - c8;
        rp8[tid] = excl;
        if (tid < nd) {
            rse[d0 + tid] = make_int2(base + excl, base + excl + c8);
            dis[d0 + tid] = rsqrtf((float)cnt[tid] + 1.0f);
        }
    }
    __syncthreads();
    const int tot8 = sc[NPB - 1];              // <= ~2700 << ESTR

    for (int i = tid; i < tot8; i += 256) buf2[i] = SENT;
    __syncthreads();
    for (int e = tid; e < count; e += 256) {
        int w = buf[e];
        int ld = w >> 20;
        int pos = rp8[ld] + atomicAdd(&fillc[ld], 1);
        buf2[pos] = w & 0xFFFFF;
    }
    __syncthreads();
    for (int e = tid; e < tot8; e += 256) esrc[base + e] = buf2[e];
}

// ---------------- MFMA GEMM (layer 0): ys[n,64] = fp16(dis[row] * (x[n,128] @ W)); block 0 zeroes sentinel ----------------

template <typename TIN, int DIN, int DOUT>
__global__ void __launch_bounds__(256) gemm_kernel(const TIN* __restrict__ x,
                                                   const __half* __restrict__ wt16,
                                                   const float* __restrict__ dis,
                                                   __half* __restrict__ ys, int n) {
    constexpr int WS = DIN + 8;
    constexpr int NT = DOUT / 16;
    constexpr int KC = DIN / 32;

    __shared__ _Float16 xls[64 * WS];
    __shared__ _Float16 wls[DOUT * WS];

    const int tid  = threadIdx.x;
    const int row0 = blockIdx.x * 64;

    if (blockIdx.x == 0 && tid < DOUT / 2)     // zero sentinel row (DOUT halves = DOUT/2 ints)
        ((int*)ys)[(long)SENT * (DOUT / 2) + tid] = 0;

    for (int i = tid; i < DOUT * DIN / 8; i += 256) {
        int c = (i * 8) / DIN, k = (i * 8) % DIN;
        *(int4*)&wls[c * WS + k] = *(const int4*)&wt16[c * DIN + k];
    }
    if constexpr (sizeof(TIN) == 4) {
        for (int i = tid; i < 64 * DIN / 4; i += 256) {
            int r = (i * 4) / DIN, k = (i * 4) % DIN;
            float4 v = make_float4(0.f, 0.f, 0.f, 0.f);
            if (row0 + r < n) v = *(const float4*)&x[(long)(row0 + r) * DIN + k];
            _Float16 h[4] = {(_Float16)v.x, (_Float16)v.y, (_Float16)v.z, (_Float16)v.w};
            *(int2*)&xls[r * WS + k] = *(int2*)h;
        }
    } else {
        for (int i = tid; i < 64 * DIN / 8; i += 256) {
            int r = (i * 8) / DIN, k = (i * 8) % DIN;
            int4 v = make_int4(0, 0, 0, 0);
            if (row0 + r < n) v = *(const int4*)&x[(long)(row0 + r) * DIN + k];
            *(int4*)&xls[r * WS + k] = v;
        }
    }
    __syncthreads();

    const int wave = tid >> 6;
    const int lane = tid & 63;
    const int m16  = lane & 15;
    const int quad = lane >> 4;

    f4v acc[NT];
#pragma unroll
    for (int t = 0; t < NT; ++t) acc[t] = (f4v){0.f, 0.f, 0.f, 0.f};

    const int arow = wave * 16 + m16;
#pragma unroll
    for (int kc = 0; kc < KC; ++kc) {
        h8 a = *(const h8*)&xls[arow * WS + kc * 32 + quad * 8];
#pragma unroll
        for (int t = 0; t < NT; ++t) {
            h8 b = *(const h8*)&wls[(t * 16 + m16) * WS + kc * 32 + quad * 8];
            acc[t] = __builtin_amdgcn_mfma_f32_16x16x32_f16(a, b, acc[t], 0, 0, 0);
        }
    }

    float dsv[4];
    int   lrow[4];
#pragma unroll
    for (int reg = 0; reg < 4; ++reg) {
        lrow[reg] = wave * 16 + quad * 4 + reg;
        int grow  = row0 + lrow[reg];
        dsv[reg]  = (grow < n) ? dis[grow] : 0.f;
    }
    __syncthreads();
    _Float16* stage = xls;
#pragma unroll
    for (int t = 0; t < NT; ++t) {
#pragma unroll
        for (int reg = 0; reg < 4; ++reg)
            stage[lrow[reg] * DOUT + t * 16 + m16] = (_Float16)(acc[t][reg] * dsv[reg]);
    }
    __syncthreads();
    for (int i = tid; i < 64 * DOUT / 8; i += 256) {
        int off = i * 8;
        int r = off / DOUT;
        if (row0 + r < n)
            *(int4*)&ys[(long)row0 * DOUT + off] = *(int4*)&stage[off];
    }
}

// ---------------- gather helper ----------------

__device__ __forceinline__ void acc8(int4 w, float* a) {
    __half2* h = (__half2*)&w;
    float2 f0 = __half22float2(h[0]);
    float2 f1 = __half22float2(h[1]);
    float2 f2 = __half22float2(h[2]);
    float2 f3 = __half22float2(h[3]);
    a[0] += f0.x; a[1] += f0.y; a[2] += f1.x; a[3] += f1.y;
    a[4] += f2.x; a[5] += f2.y; a[6] += f3.x; a[7] += f3.y;
}

// ---------------- FUSED gather(64) + GEMM(64->DOUT); index-prefetch pipelined gather loop ----------------

template <int DOUT>
__global__ void __launch_bounds__(256) fused_gg_kernel(const int2* __restrict__ rse, const int* __restrict__ esrc,
                                                       const __half* __restrict__ ysin, const float* __restrict__ dis,
                                                       const float* __restrict__ bvec, const __half* __restrict__ wt16,
                                                       __half* __restrict__ ysout, int n) {
    constexpr int WS = 72;
    constexpr int NT = DOUT / 16;

    __shared__ _Float16 xls[64 * WS];
    __shared__ _Float16 wls[DOUT * WS];

    const int tid  = threadIdx.x;
    const int row0 = blockIdx.x * 64;

    if (blockIdx.x == 0 && tid < DOUT / 2)
        ((int*)ysout)[(long)SENT * (DOUT / 2) + tid] = 0;

    for (int i = tid; i < DOUT * 64 / 8; i += 256) {
        int c = (i * 8) / 64, k = (i * 8) % 64;
        *(int4*)&wls[c * WS + k] = *(const int4*)&wt16[c * 64 + k];
    }

    // ---- phase A: gather (pipelined, branch-free 8-wide over padded segments) ----
#pragma unroll
    for (int pass = 0; pass < 2; ++pass) {
        const int lrow = pass * 32 + (tid >> 3);
        const int node = row0 + lrow;
        const int sel  = (tid & 7) * 8;
        float a[8] = {0.f, 0.f, 0.f, 0.f, 0.f, 0.f, 0.f, 0.f};
        if (node < n) {
            {
                int4 sw = *(const int4*)&ysin[(long)node * 64 + sel];
                acc8(sw, a);
            }
            const int2 se = rse[node];
            int k = se.x;
            const int kend = se.y;
            if (k < kend) {
                int u0 = esrc[k + 0], u1 = esrc[k + 1], u2 = esrc[k + 2], u3 = esrc[k + 3];
                int u4 = esrc[k + 4], u5 = esrc[k + 5], u6 = esrc[k + 6], u7 = esrc[k + 7];
                for (k += 8; k < kend; k += 8) {
                    int v0 = esrc[k + 0], v1 = esrc[k + 1], v2 = esrc[k + 2], v3 = esrc[k + 3];
                    int v4 = esrc[k + 4], v5 = esrc[k + 5], v6 = esrc[k + 6], v7 = esrc[k + 7];
                    int4 w0 = *(const int4*)&ysin[(long)u0 * 64 + sel];
                    int4 w1 = *(const int4*)&ysin[(long)u1 * 64 + sel];
                    int4 w2 = *(const int4*)&ysin[(long)u2 * 64 + sel];
                    int4 w3 = *(const int4*)&ysin[(long)u3 * 64 + sel];
                    int4 w4 = *(const int4*)&ysin[(long)u4 * 64 + sel];
                    int4 w5 = *(const int4*)&ysin[(long)u5 * 64 + sel];
                    int4 w6 = *(const int4*)&ysin[(long)u6 * 64 + sel];
                    int4 w7 = *(const int4*)&ysin[(long)u7 * 64 + sel];
                    acc8(w0, a); acc8(w1, a); acc8(w2, a); acc8(w3, a);
                    acc8(w4, a); acc8(w5, a); acc8(w6, a); acc8(w7, a);
                    u0 = v0; u1 = v1; u2 = v2; u3 = v3;
                    u4 = v4; u5 = v5; u6 = v6; u7 = v7;
                }
                int4 w0 = *(const int4*)&ysin[(long)u0 * 64 + sel];
                int4 w1 = *(const int4*)&ysin[(long)u1 * 64 + sel];
                int4 w2 = *(const int4*)&ysin[(long)u2 * 64 + sel];
                int4 w3 = *(const int4*)&ysin[(long)u3 * 64 + sel];
                int4 w4 = *(const int4*)&ysin[(long)u4 * 64 + sel];
                int4 w5 = *(const int4*)&ysin[(long)u5 * 64 + sel];
                int4 w6 = *(const int4*)&ysin[(long)u6 * 64 + sel];
                int4 w7 = *(const int4*)&ysin[(long)u7 * 64 + sel];
                acc8(w0, a); acc8(w1, a); acc8(w2, a); acc8(w3, a);
                acc8(w4, a); acc8(w5, a); acc8(w6, a); acc8(w7, a);
            }
            const float di = dis[node];
#pragma unroll
            for (int j = 0; j < 8; ++j)
                a[j] = fmaxf(a[j] * di + bvec[sel + j], 0.0f);
        }
        _Float16 hv[8];
#pragma unroll
        for (int j = 0; j < 8; ++j) hv[j] = (_Float16)a[j];
        *(int4*)&xls[lrow * WS + sel] = *(int4*)hv;
    }
    __syncthreads();

    // ---- phase B: GEMM ----
    const int wave = tid >> 6;
    const int lane = tid & 63;
    const int m16  = lane & 15;
    const int quad = lane >> 4;

    f4v acc[NT];
#pragma unroll
    for (int t = 0; t < NT; ++t) acc[t] = (f4v){0.f, 0.f, 0.f, 0.f};

    const int arow = wave * 16 + m16;
#pragma unroll
    for (int kc = 0; kc < 2; ++kc) {
        h8 av = *(const h8*)&xls[arow * WS + kc * 32 + quad * 8];
#pragma unroll
        for (int t = 0; t < NT; ++t) {
            h8 bv = *(const h8*)&wls[(t * 16 + m16) * WS + kc * 32 + quad * 8];
            acc[t] = __builtin_amdgcn_mfma_f32_16x16x32_f16(av, bv, acc[t], 0, 0, 0);
        }
    }

    float dsv[4];
    int   lr[4];
#pragma unroll
    for (int reg = 0; reg < 4; ++reg) {
        lr[reg]  = wave * 16 + quad * 4 + reg;
        int grow = row0 + lr[reg];
        dsv[reg] = (grow < n) ? dis[grow] : 0.f;
    }
    __syncthreads();
    _Float16* stage = wls;
#pragma unroll
    for (int t = 0; t < NT; ++t) {
#pragma unroll
        for (int reg = 0; reg < 4; ++reg)
            stage[lr[reg] * DOUT + t * 16 + m16] = (_Float16)(acc[t][reg] * dsv[reg]);
    }
    __syncthreads();
    for (int i = tid; i < 64 * DOUT / 8; i += 256) {
        int off = i * 8;
        int r = off / DOUT;
        if (row0 + r < n)
            *(int4*)&ysout[(long)row0 * DOUT + off] = *(int4*)&stage[off];
    }
}

// ---------------- final gather (32-wide), pipelined, fp32 out ----------------

__global__ void __launch_bounds__(256) gather4h_kernel(const int2* __restrict__ rse, const int* __restrict__ esrc,
                                                       const __half* __restrict__ ys, const float* __restrict__ dis,
                                                       const float* __restrict__ b, float* __restrict__ out, int n) {
    const int node = blockIdx.x * 64 + (threadIdx.x >> 2);
    const int c = (threadIdx.x & 3) * 8;
    if (node >= n) return;

    float a[8];
    {
        int4 sw = *(const int4*)&ys[(long)node * 32 + c];
        __half2* h = (__half2*)&sw;
        float2 f0 = __half22float2(h[0]);
        float2 f1 = __half22float2(h[1]);
        float2 f2 = __half22float2(h[2]);
        float2 f3 = __half22float2(h[3]);
        a[0] = f0.x; a[1] = f0.y; a[2] = f1.x; a[3] = f1.y;
        a[4] = f2.x; a[5] = f2.y; a[6] = f3.x; a[7] = f3.y;
    }

    const int2 se = rse[node];
    int k = se.x;
    const int kend = se.y;
    if (k < kend) {
        int u0 = esrc[k + 0], u1 = esrc[k + 1], u2 = esrc[k + 2], u3 = esrc[k + 3];
        int u4 = esrc[k + 4], u5 = esrc[k + 5], u6 = esrc[k + 6], u7 = esrc[k + 7];
        for (k += 8; k < kend; k += 8) {
            int v0 = esrc[k + 0], v1 = esrc[k + 1], v2 = esrc[k + 2], v3 = esrc[k + 3];
            int v4 = esrc[k + 4], v5 = esrc[k + 5], v6 = esrc[k + 6], v7 = esrc[k + 7];
            int4 w0 = *(const int4*)&ys[(long)u0 * 32 + c];
            int4 w1 = *(const int4*)&ys[(long)u1 * 32 + c];
            int4 w2 = *(const int4*)&ys[(long)u2 * 32 + c];
            int4 w3 = *(const int4*)&ys[(long)u3 * 32 + c];
            int4 w4 = *(const int4*)&ys[(long)u4 * 32 + c];
            int4 w5 = *(const int4*)&ys[(long)u5 * 32 + c];
            int4 w6 = *(const int4*)&ys[(long)u6 * 32 + c];
            int4 w7 = *(const int4*)&ys[(long)u7 * 32 + c];
            acc8(w0, a); acc8(w1, a); acc8(w2, a); acc8(w3, a);
            acc8(w4, a); acc8(w5, a); acc8(w6, a); acc8(w7, a);
            u0 = v0; u1 = v1; u2 = v2; u3 = v3;
            u4 = v4; u5 = v5; u6 = v6; u7 = v7;
        }
        int4 w0 = *(const int4*)&ys[(long)u0 * 32 + c];
        int4 w1 = *(const int4*)&ys[(long)u1 * 32 + c];
        int4 w2 = *(const int4*)&ys[(long)u2 * 32 + c];
        int4 w3 = *(const int4*)&ys[(long)u3 * 32 + c];
        int4 w4 = *(const int4*)&ys[(long)u4 * 32 + c];
        int4 w5 = *(const int4*)&ys[(long)u5 * 32 + c];
        int4 w6 = *(const int4*)&ys[(long)u6 * 32 + c];
        int4 w7 = *(const int4*)&ys[(long)u7 * 32 + c];
        acc8(w0, a); acc8(w1, a); acc8(w2, a); acc8(w3, a);
        acc8(w4, a); acc8(w5, a); acc8(w6, a); acc8(w7, a);
    }

    const float di = dis[node];
    float4 o0, o1;
    o0.x = a[0] * di + b[c + 0];
    o0.y = a[1] * di + b[c + 1];
    o0.z = a[2] * di + b[c + 2];
    o0.w = a[3] * di + b[c + 3];
    o1.x = a[4] * di + b[c + 4];
    o1.y = a[5] * di + b[c + 5];
    o1.z = a[6] * di + b[c + 6];
    o1.w = a[7] * di + b[c + 7];
    *(float4*)&out[(long)node * 32 + c] = o0;
    *(float4*)&out[(long)node * 32 + c + 4] = o1;
}

// ---------------- launch ----------------

extern "C" void kernel_launch(void* const* d_in, const int* in_sizes, int n_in,
                              void* d_out, int out_size, void* d_ws, size_t ws_size,
                              hipStream_t stream) {
    const float* features = (const float*)d_in[0];
    const int*   ei       = (const int*)d_in[1];
    const float* W0 = (const float*)d_in[2];
    const float* b0 = (const float*)d_in[3];
    const float* W1 = (const float*)d_in[4];
    const float* b1 = (const float*)d_in[5];
    const float* W2 = (const float*)d_in[6];
    const float* b2 = (const float*)d_in[7];

    const int* src = ei;             // edge_index[0]
    const int* dst = ei + N_EDGES;   // edge_index[1]

    const int n = N_NODES;

    // workspace (int slots). Aliases (stream-ordered, verified):
    //   tmp aliases ysB (tmp dead after bucketfin; ysB first written by fused#1)
    //   ysC aliases ysA (ysA dead after fused#1; ysC first written by fused#2)
    int*    L    = (int*)d_ws;                        // 256*783 = 200448 -> [0, 200448)
    float*  dis  = (float*)d_ws + 200448;             // [200448, 300800)
    int2*   rse  = (int2*)((int*)d_ws + 300800);      // n int2 = 200704 ints -> [300800, 501504)
    int*    esrc = (int*)d_ws + 501504;               // 782*3072 = 2402304 -> [501504, 2903808)
    __half* ysA  = (__half*)((int*)d_ws + 2903808);   // 100001*64 halves = 3200032 ints
    __half* ysC  = (__half*)((int*)d_ws + 2903808);   // alias
    __half* ysB  = (__half*)((int*)d_ws + 6103840);   // 3200032 ints
    int*    tmp  = (int*)d_ws + 6103840;              // alias (1600000 ints)
    __half* wt0  = (__half*)((int*)d_ws + 9303872);   // 8192 halves
    __half* wt1  = (__half*)((int*)d_ws + 9307968);   // 4096 halves
    __half* wt2  = (__half*)((int*)d_ws + 9310016);   // 2048 halves
    float*  outf = (float*)d_out;                     // N*32 fp32

    // ---- CSR build (2 kernels) ----
    build_kernel<<<FBLK + 1, 256, 0, stream>>>(src, dst, L, tmp, W0, W1, W2, wt0, wt1, wt2);
    bucketfin_kernel<<<NBK, 256, 0, stream>>>(tmp, L, esrc, rse, dis, n);

    // ---- layer 0 GEMM: features(fp32,128) -> ysA ----
    gemm_kernel<float, 128, 64><<<(n + 63) / 64, 256, 0, stream>>>(features, wt0, dis, ysA, n);

    // ---- fused gather(L0)+ReLU+GEMM(L1): ysA -> ysB ----
    fused_gg_kernel<64><<<(n + 63) / 64, 256, 0, stream>>>(rse, esrc, ysA, dis, b0, wt1, ysB, n);

    // ---- fused gather(L1)+ReLU+GEMM(L2): ysB -> ysC ----
    fused_gg_kernel<32><<<(n + 63) / 64, 256, 0, stream>>>(rse, esrc, ysB, dis, b1, wt2, ysC, n);

    // ---- final gather(L2), no ReLU, fp32 out ----
    gather4h_kernel<<<(n + 63) / 64, 256, 0, stream>>>(rse, esrc, ysC, dis, b2, outf, n);
}